// Round 1
// baseline (490.432 us; speedup 1.0000x reference)
//
#include <hip/hip_runtime.h>
#include <math.h>

#define NN 100000
#define FEAT 128
#define NHEAD 4
#define BSH 9                      // 512 nodes per bucket
#define BNODES 512
#define NBUCK 196                  // ceil(NN / 512)
#define BCAP 16384                 // colidx LDS image capacity (avg span ~8700)
#define PA_EPT 16                  // phase-A edges per thread
#define GTILES 6250                // 100000 / 16
#define GEMMB 512                  // gemm grid blocks
#define HSTRIDE 136                // h-staging row stride (ushorts)
#define SRCMASK 0x1FFFF            // low 17 bits: src id (NN < 2^17)

typedef unsigned int uint;
typedef unsigned short ushort;
typedef __attribute__((ext_vector_type(8))) short short8;
typedef __attribute__((ext_vector_type(4))) float fx4;

__device__ __forceinline__ float lrelu(float v) { return v > 0.f ? v : 0.2f * v; }

__device__ __forceinline__ ushort f2bf(float f) {          // RNE bf16
    uint u = __float_as_uint(f);
    return (ushort)((u + 0x7fffu + ((u >> 16) & 1u)) >> 16);
}
__device__ __forceinline__ float bf_lo(uint u) { return __uint_as_float(u << 16); }
__device__ __forceinline__ float bf_hi(uint u) { return __uint_as_float(u & 0xffff0000u); }

__device__ __forceinline__ short8 pack8f(const float* p) {
    float4 a = *(const float4*)p, b = *(const float4*)(p + 4);
    short8 v;
    v[0] = (short)f2bf(a.x); v[1] = (short)f2bf(a.y);
    v[2] = (short)f2bf(a.z); v[3] = (short)f2bf(a.w);
    v[4] = (short)f2bf(b.x); v[5] = (short)f2bf(b.y);
    v[6] = (short)f2bf(b.z); v[7] = (short)f2bf(b.w);
    return v;
}

// ---- MFMA GEMM body (r12 structure; no B-prefetch — regressed twice r8/r11) ----
template <bool FP32IN>
__device__ __forceinline__ void gemm_body(
    const void* __restrict__ in, const float* __restrict__ W,
    const float* __restrict__ a_src, const float* __restrict__ a_dst,
    ushort* __restrict__ hbf, float* __restrict__ al_s, float* __restrict__ al_d,
    int bid, int gridn)
{
    __shared__ __align__(16) ushort WA[FEAT * FEAT];       // 32 KiB, fragment-ordered
    __shared__ __align__(16) ushort HS[4][16 * HSTRIDE];   // 17 KiB, per-wave h staging
    const int t = threadIdx.x;
    for (int idx = t; idx < FEAT * FEAT; idx += 256) {
        int k = idx >> 7, m = idx & 127;
        int mt = m >> 4, kt = k >> 5, qq = (k >> 3) & 3, j = k & 7;
        int ln = qq * 16 + (m & 15);
        WA[((mt * 4 + kt) * 64 + ln) * 8 + j] = f2bf(W[idx]);
    }
    __syncthreads();

    const int wv = t >> 6, lane = t & 63;
    const int node_l = lane & 15, q = lane >> 4;

    short8 afr[8][4];
    #pragma unroll
    for (int mt = 0; mt < 8; ++mt)
        #pragma unroll
        for (int kt = 0; kt < 4; ++kt)
            afr[mt][kt] = *(const short8*)&WA[((mt * 4 + kt) * 64 + lane) * 8];

    const ushort* inbf = (const ushort*)in;
    const float*  inf  = (const float*)in;

    for (int tile = bid * 4 + wv; tile < GTILES; tile += gridn * 4) {
        const int n0 = tile * 16;
        short8 b0, b1, b2, b3;
        if (FP32IN) {
            const float* rf = inf + (size_t)(n0 + node_l) * FEAT + q * 8;
            b0 = pack8f(rf);
            b1 = pack8f(rf + 32);
            b2 = pack8f(rf + 64);
            b3 = pack8f(rf + 96);
        } else {
            const ushort* rowp = inbf + (size_t)(n0 + node_l) * FEAT + q * 8;
            b0 = *(const short8*)(rowp);
            b1 = *(const short8*)(rowp + 32);
            b2 = *(const short8*)(rowp + 64);
            b3 = *(const short8*)(rowp + 96);
        }
        fx4 zero = {0.f, 0.f, 0.f, 0.f};
        fx4 acc[8];
        #pragma unroll
        for (int mt = 0; mt < 8; ++mt) acc[mt] = zero;
        #pragma unroll
        for (int kt = 0; kt < 4; ++kt) {
            short8 b = (kt == 0) ? b0 : (kt == 1) ? b1 : (kt == 2) ? b2 : b3;
            #pragma unroll
            for (int mt = 0; mt < 8; ++mt)
                acc[mt] = __builtin_amdgcn_mfma_f32_16x16x32_bf16(afr[mt][kt], b, acc[mt], 0, 0, 0);
        }
        float ps[4] = {0.f, 0.f, 0.f, 0.f};
        float pd[4] = {0.f, 0.f, 0.f, 0.f};
        #pragma unroll
        for (int mt = 0; mt < 8; ++mt) {
            float4 as4 = *(const float4*)(a_src + mt * 16 + q * 4);
            float4 ad4 = *(const float4*)(a_dst + mt * 16 + q * 4);
            ps[mt >> 1] += acc[mt][0] * as4.x + acc[mt][1] * as4.y + acc[mt][2] * as4.z + acc[mt][3] * as4.w;
            pd[mt >> 1] += acc[mt][0] * ad4.x + acc[mt][1] * ad4.y + acc[mt][2] * ad4.z + acc[mt][3] * ad4.w;
            ushort4 hv;
            hv.x = f2bf(acc[mt][0]); hv.y = f2bf(acc[mt][1]);
            hv.z = f2bf(acc[mt][2]); hv.w = f2bf(acc[mt][3]);
            *(ushort4*)&HS[wv][node_l * HSTRIDE + mt * 16 + q * 4] = hv;
        }
        #pragma unroll
        for (int h = 0; h < 4; ++h) {
            ps[h] += __shfl_xor(ps[h], 16); ps[h] += __shfl_xor(ps[h], 32);
            pd[h] += __shfl_xor(pd[h], 16); pd[h] += __shfl_xor(pd[h], 32);
        }
        float vs = (q == 0) ? ps[0] : (q == 1) ? ps[1] : (q == 2) ? ps[2] : ps[3];
        float vd = (q == 0) ? pd[0] : (q == 1) ? pd[1] : (q == 2) ? pd[2] : pd[3];
        al_s[(n0 + node_l) * 4 + q] = vs;
        al_d[(n0 + node_l) * 4 + q] = vd;
        #pragma unroll
        for (int it = 0; it < 4; ++it) {
            int fi = it * 64 + lane;
            int row = fi >> 4, colc = fi & 15;
            short8 v = *(const short8*)&HS[wv][row * HSTRIDE + colc * 8];
            *(short8*)(hbf + (size_t)n0 * FEAT + (size_t)fi * 8) = v;
        }
    }
}

// ---- phase-A body: bucket-binned (dst,src) pair scatter ----
__device__ __forceinline__ void phaseA_body(
    const int* __restrict__ ei, int E, int* bcursor, uint* __restrict__ pairs, int bid)
{
    __shared__ int lh[NBUCK], lb[NBUCK];
    int t = threadIdx.x;
    if (t < NBUCK) lh[t] = 0;
    __syncthreads();
    int base = bid * (256 * PA_EPT) + t;
    int s[PA_EPT], d[PA_EPT];
    #pragma unroll
    for (int k = 0; k < PA_EPT; ++k) {
        int i = base + k * 256;
        if (i < E)            { s[k] = ei[i]; d[k] = ei[E + i]; }
        else if (i < E + NN)  { s[k] = i - E; d[k] = s[k]; }
        else                  { s[k] = 0; d[k] = -1; }
        if (d[k] >= 0) atomicAdd(&lh[d[k] >> BSH], 1);
    }
    __syncthreads();
    if (t < NBUCK) {
        int c = lh[t];
        lb[t] = c ? atomicAdd(&bcursor[t], c) : 0;
        lh[t] = 0;
    }
    __syncthreads();
    #pragma unroll
    for (int k = 0; k < PA_EPT; ++k) {
        if (d[k] >= 0) {
            int b = d[k] >> BSH;
            int off = atomicAdd(&lh[b], 1);
            pairs[lb[b] + off] = ((uint)(d[k] & (BNODES - 1)) << 17) | (uint)s[k];
        }
    }
}

// ---- standalone gemm (layers 1,2) ----
__global__ __launch_bounds__(256, 2) void gemm_mfma_kernel(
    const void* __restrict__ in, const float* __restrict__ W,
    const float* __restrict__ a_src, const float* __restrict__ a_dst,
    ushort* __restrict__ hbf, float* __restrict__ al_s, float* __restrict__ al_d)
{
    gemm_body<false>(in, W, a_src, a_dst, hbf, al_s, al_d, blockIdx.x, GEMMB);
}

// ---- fused: gemm layer 0 (fp32 in) || CSR phase A (data-independent) ----
__global__ __launch_bounds__(256, 2) void gemm0_phaseA_kernel(
    const float* __restrict__ x, const float* __restrict__ W,
    const float* __restrict__ a_src, const float* __restrict__ a_dst,
    ushort* __restrict__ hbf, float* __restrict__ al_s, float* __restrict__ al_d,
    const int* __restrict__ ei, int E, int* bcursor, uint* __restrict__ pairs)
{
    if (blockIdx.x < GEMMB)
        gemm_body<true>(x, W, a_src, a_dst, hbf, al_s, al_d, blockIdx.x, GEMMB);
    else
        phaseA_body(ei, E, bcursor, pairs, blockIdx.x - GEMMB);
}

// ======================= CSR build (rest) =======================

__global__ __launch_bounds__(256) void bucket_hist_kernel(
    const int* __restrict__ ei, int E, int* bsize)
{
    __shared__ int lh[NBUCK];
    int t = threadIdx.x;
    if (t < NBUCK) lh[t] = 0;
    __syncthreads();
    int stride = gridDim.x * 256;
    for (int i = blockIdx.x * 256 + t; i < E + NN; i += stride) {
        int d = (i < E) ? ei[E + i] : (i - E);
        atomicAdd(&lh[d >> BSH], 1);
    }
    __syncthreads();
    if (t < NBUCK && lh[t]) atomicAdd(&bsize[t], lh[t]);
}

__global__ __launch_bounds__(256) void bucket_scan_kernel(
    const int* __restrict__ bsize, int* bbase, int* bcursor)
{
    __shared__ int sm[256];
    int t = threadIdx.x;
    int v = (t < NBUCK) ? bsize[t] : 0;
    sm[t] = v;
    __syncthreads();
    #pragma unroll
    for (int off = 1; off < 256; off <<= 1) {
        int x = (t >= off) ? sm[t - off] : 0;
        __syncthreads();
        sm[t] += x;
        __syncthreads();
    }
    if (t < NBUCK) {
        int excl = sm[t] - v;
        bbase[t] = excl;
        bcursor[t] = excl;
    }
    if (t == 255) bbase[NBUCK] = sm[255];
}

__global__ __launch_bounds__(256) void phaseB_kernel(
    const uint* __restrict__ pairs, const int* __restrict__ bbase,
    int* __restrict__ row_ptr, int* __restrict__ colidx, int EP)
{
    __shared__ int nh[BNODES];
    __shared__ int ex[BNODES];
    __shared__ int ss[256];
    __shared__ int img[BCAP];
    int b = blockIdx.x, t = threadIdx.x;
    int node0 = b << BSH;
    int nend = min(NN - node0, BNODES);
    int pb = bbase[b], pe = bbase[b + 1];
    int span = pe - pb;
    for (int j = t; j < BNODES; j += 256) nh[j] = 0;
    __syncthreads();
    for (int i = t; i < span; i += 256)
        atomicAdd(&nh[pairs[pb + i] >> 17], 1);
    __syncthreads();
    int v0 = nh[2 * t], v1 = nh[2 * t + 1];
    int psc = v0 + v1;
    ss[t] = psc;
    __syncthreads();
    #pragma unroll
    for (int off = 1; off < 256; off <<= 1) {
        int x = (t >= off) ? ss[t - off] : 0;
        __syncthreads();
        ss[t] += x;
        __syncthreads();
    }
    int ep = ss[t] - psc;
    ex[2 * t] = ep;
    ex[2 * t + 1] = ep + v0;
    __syncthreads();
    for (int j = t; j < nend; j += 256) row_ptr[node0 + j] = pb + ex[j];
    if (b == NBUCK - 1 && t == 0) row_ptr[NN] = EP;
    for (int j = t; j < BNODES; j += 256) nh[j] = ex[j];   // reuse as cursors
    __syncthreads();
    if (span <= BCAP) {
        for (int i = t; i < span; i += 256) {
            uint p = pairs[pb + i];
            int pos = atomicAdd(&nh[p >> 17], 1);
            img[pos] = (int)(p & SRCMASK);
        }
        __syncthreads();
        for (int i = t; i < span; i += 256) colidx[pb + i] = img[i];
    } else {
        for (int i = t; i < span; i += 256) {
            uint p = pairs[pb + i];
            int pos = atomicAdd(&nh[p >> 17], 1);
            colidx[pb + pos] = (int)(p & SRCMASK);
        }
    }
}

// ======================= fused softmax + aggregation =======================
// LAST=false: writes bf16 y. LAST=true: fuses final FC(128->10)+log_softmax.
// r13: depth-2 software pipeline on 4-edge batches + exp dedup (1 exp/edge/quad,
//      broadcast via shfl) — attacks exposed gather latency (VALU 47 / HBM 36).
#define AGGR_STEP(hv, wgt)                                                    \
    a0 = fmaf(wgt, bf_lo(hv.x), a0); a1 = fmaf(wgt, bf_hi(hv.x), a1);        \
    a2 = fmaf(wgt, bf_lo(hv.y), a2); a3 = fmaf(wgt, bf_hi(hv.y), a3);        \
    a4 = fmaf(wgt, bf_lo(hv.z), a4); a5 = fmaf(wgt, bf_hi(hv.z), a5);        \
    a6 = fmaf(wgt, bf_lo(hv.w), a6); a7 = fmaf(wgt, bf_hi(hv.w), a7);

// issue gathers for a 4-edge batch: per-lane al_s value for edge (lane&3)
// of this lane's head, plus the 4 h rows (16B per lane each).
#define GATHER4(c, hv, av)                                                    \
    {                                                                         \
        int sx = (sub == 0) ? c.x : (sub == 1) ? c.y : (sub == 2) ? c.z : c.w;\
        av = al_s[sx * 4 + head];                                             \
        hv[0] = ((const uint4*)(hbf + (size_t)c.x * FEAT))[lane];             \
        hv[1] = ((const uint4*)(hbf + (size_t)c.y * FEAT))[lane];             \
        hv[2] = ((const uint4*)(hbf + (size_t)c.z * FEAT))[lane];             \
        hv[3] = ((const uint4*)(hbf + (size_t)c.w * FEAT))[lane];             \
    }

// consume a gathered batch: one exp chain per lane, broadcast the 4 weights
// across the head-quad via shfl(width=16), then accumulate.
#define ACCUM4(hv, av)                                                        \
    {                                                                         \
        float ww = __expf(lrelu(av + ald_h));                                 \
        float w0 = __shfl(ww, qbase | 0, 16);                                 \
        float w1 = __shfl(ww, qbase | 1, 16);                                 \
        float w2 = __shfl(ww, qbase | 2, 16);                                 \
        float w3 = __shfl(ww, qbase | 3, 16);                                 \
        ssum += (w0 + w1) + (w2 + w3);                                        \
        AGGR_STEP(hv[0], w0) AGGR_STEP(hv[1], w1)                             \
        AGGR_STEP(hv[2], w2) AGGR_STEP(hv[3], w3)                             \
    }

template <bool LAST>
__global__ __launch_bounds__(256) void aggr_csr_kernel(
    const int* __restrict__ row_ptr, const int* __restrict__ colidx,
    const ushort* __restrict__ hbf, const float* __restrict__ al_s,
    const float* __restrict__ al_d, const float* __restrict__ bias,
    ushort* __restrict__ outbf,
    const float* __restrict__ fcW, const float* __restrict__ fcb,
    float* __restrict__ logout)
{
    __shared__ float WT[10][FEAT];   // used only when LAST
    __shared__ float bl[10];
    int t = threadIdx.x;
    if (LAST) {
        for (int i = t; i < FEAT * 10; i += 256) {
            int k = i / 10, c = i % 10;
            WT[c][k] = fcW[i];
        }
        if (t < 10) bl[t] = fcb[t];
        __syncthreads();
    }
    int node = blockIdx.x * 16 + (t >> 4);
    int lane = t & 15;
    int head = lane >> 2;
    const int sub = lane & 3;
    const int qbase = lane & 12;
    float ald_h = al_d[node * 4 + head];
    int beg = row_ptr[node], end = row_ptr[node + 1];

    float ssum = 0.f;
    float a0=0.f,a1=0.f,a2=0.f,a3=0.f,a4=0.f,a5=0.f,a6=0.f,a7=0.f;

    const int nb = (end - beg) >> 2;   // full 4-edge batches
    int4 c0, c1;
    uint4 h0[4], h1[4];
    float av0 = 0.f, av1 = 0.f;
    if (nb >= 1) { c0 = *(const int4*)&colidx[beg];     GATHER4(c0, h0, av0) }
    if (nb >= 2) { c1 = *(const int4*)&colidx[beg + 4]; GATHER4(c1, h1, av1) }
    int i = 0;
    for (; i + 3 < nb; i += 2) {
        int4 cn0 = *(const int4*)&colidx[beg + (i + 2) * 4];
        int4 cn1 = *(const int4*)&colidx[beg + (i + 3) * 4];
        ACCUM4(h0, av0)                // consume batch i (gathered 2 iters ago)
        GATHER4(cn0, h0, av0)          // issue batch i+2
        ACCUM4(h1, av1)                // consume batch i+1
        GATHER4(cn1, h1, av1)          // issue batch i+3
    }
    if (i + 2 < nb) {                  // 3 batches left: i, i+1, i+2
        int4 cn0 = *(const int4*)&colidx[beg + (i + 2) * 4];
        ACCUM4(h0, av0)
        GATHER4(cn0, h0, av0)
        ACCUM4(h1, av1)
        ACCUM4(h0, av0)
    } else if (i + 1 < nb) {           // 2 left
        ACCUM4(h0, av0)
        ACCUM4(h1, av1)
    } else if (i < nb) {               // 1 left
        ACCUM4(h0, av0)
    }
    for (int p = beg + nb * 4; p < end; ++p) {   // scalar tail (0-3 edges)
        int sn = colidx[p];
        float wq = __expf(lrelu(al_s[sn*4 + head] + ald_h));
        uint4 hv = ((const uint4*)(hbf + (size_t)sn * FEAT))[lane];
        ssum += wq;
        AGGR_STEP(hv, wq)
    }

    float inv = 1.f / (ssum + 1e-16f);
    const float* bp = bias + lane * 8;
    float o[8] = {a0,a1,a2,a3,a4,a5,a6,a7};
    #pragma unroll
    for (int k = 0; k < 8; ++k) {
        float v = o[k] * inv + bp[k];
        o[k] = v > 0.f ? v : __expf(v) - 1.f;
    }
    if (!LAST) {
        uint4 u;
        u.x = (uint)f2bf(o[0]) | ((uint)f2bf(o[1]) << 16);
        u.y = (uint)f2bf(o[2]) | ((uint)f2bf(o[3]) << 16);
        u.z = (uint)f2bf(o[4]) | ((uint)f2bf(o[5]) << 16);
        u.w = (uint)f2bf(o[6]) | ((uint)f2bf(o[7]) << 16);
        ((uint4*)(outbf + (size_t)node * FEAT))[lane] = u;
    } else {
        // per-lane partial logits over this lane's 8 dims, reduce across 16 lanes
        float lg[10];
        #pragma unroll
        for (int c = 0; c < 10; ++c) {
            const float* wr = &WT[c][lane * 8];
            float4 wa = *(const float4*)(wr);
            float4 wb = *(const float4*)(wr + 4);
            float acc = fmaf(o[0], wa.x, fmaf(o[1], wa.y, fmaf(o[2], wa.z, o[3] * wa.w)));
            acc = fmaf(o[4], wb.x, fmaf(o[5], wb.y, fmaf(o[6], wb.z, fmaf(o[7], wb.w, acc))));
            lg[c] = acc;
        }
        #pragma unroll
        for (int c = 0; c < 10; ++c) {
            lg[c] += __shfl_xor(lg[c], 1, 16);
            lg[c] += __shfl_xor(lg[c], 2, 16);
            lg[c] += __shfl_xor(lg[c], 4, 16);
            lg[c] += __shfl_xor(lg[c], 8, 16);
        }
        if (lane == 0) {
            float mx = -1e30f;
            #pragma unroll
            for (int c = 0; c < 10; ++c) { lg[c] += bl[c]; mx = fmaxf(mx, lg[c]); }
            float se = 0.f;
            #pragma unroll
            for (int c = 0; c < 10; ++c) se += __expf(lg[c] - mx);
            float lse = mx + __logf(se);
            float2* op = (float2*)(logout + (size_t)node * 10);
            #pragma unroll
            for (int c = 0; c < 5; ++c)
                op[c] = make_float2(lg[2*c] - lse, lg[2*c + 1] - lse);
        }
    }
}

extern "C" void kernel_launch(void* const* d_in, const int* in_sizes, int n_in,
                              void* d_out, int out_size, void* d_ws, size_t ws_size,
                              hipStream_t stream)
{
    const float* x   = (const float*)d_in[0];
    const int*   ei  = (const int*)d_in[1];
    const float* W[3]   = {(const float*)d_in[2], (const float*)d_in[6],  (const float*)d_in[10]};
    const float* asr[3] = {(const float*)d_in[3], (const float*)d_in[7],  (const float*)d_in[11]};
    const float* ads[3] = {(const float*)d_in[4], (const float*)d_in[8],  (const float*)d_in[12]};
    const float* bs[3]  = {(const float*)d_in[5], (const float*)d_in[9],  (const float*)d_in[13]};
    const float* fcW = (const float*)d_in[14];
    const float* fcb = (const float*)d_in[15];
    const int E  = in_sizes[1] / 2;
    const int EP = E + NN;

    // workspace layout
    ushort* hbf  = (ushort*)d_ws;                      // [NN*FEAT] bf16 (gemm out)
    ushort* ybf  = hbf + (size_t)NN * FEAT;            // [NN*FEAT] bf16 (aggr out)
    float* als   = (float*)(ybf + (size_t)NN * FEAT);  // [NN*4]
    float* ald   = als + (size_t)NN * NHEAD;           // [NN*4]
    int* row_ptr = (int*)(ald + (size_t)NN * NHEAD);   // [NN+1]
    int* bsize   = row_ptr + NN + 1;                   // [NBUCK]
    int* bbase   = bsize + NBUCK;                      // [NBUCK+1]
    int* bcursor = bbase + NBUCK + 1;                  // [NBUCK]
    uint* pairs  = (uint*)(bcursor + NBUCK);           // [EP] packed
    int* colidx  = (int*)(pairs + (size_t)EP);         // [EP]

    const int pab = (EP + 256 * PA_EPT - 1) / (256 * PA_EPT);

    // ---- CSR build head ----
    hipMemsetAsync(bsize, 0, NBUCK * sizeof(int), stream);
    bucket_hist_kernel<<<1024, 256, 0, stream>>>(ei, E, bsize);
    bucket_scan_kernel<<<1, 256, 0, stream>>>(bsize, bbase, bcursor);

    // ---- layer 0 gemm (fp32 in) overlapped with CSR phase A ----
    gemm0_phaseA_kernel<<<GEMMB + pab, 256, 0, stream>>>(
        x, W[0], asr[0], ads[0], hbf, als, ald, ei, E, bcursor, pairs);
    phaseB_kernel<<<NBUCK, 256, 0, stream>>>(pairs, bbase, row_ptr, colidx, EP);

    aggr_csr_kernel<false><<<(NN + 15) / 16, 256, 0, stream>>>(
        row_ptr, colidx, hbf, als, ald, bs[0], ybf, nullptr, nullptr, nullptr);

    gemm_mfma_kernel<<<GEMMB, 256, 0, stream>>>(ybf, W[1], asr[1], ads[1], hbf, als, ald);
    aggr_csr_kernel<false><<<(NN + 15) / 16, 256, 0, stream>>>(
        row_ptr, colidx, hbf, als, ald, bs[1], ybf, nullptr, nullptr, nullptr);

    gemm_mfma_kernel<<<GEMMB, 256, 0, stream>>>(ybf, W[2], asr[2], ads[2], hbf, als, ald);
    aggr_csr_kernel<true><<<(NN + 15) / 16, 256, 0, stream>>>(
        row_ptr, colidx, hbf, als, ald, bs[2], nullptr, fcW, fcb, (float*)d_out);
}